// Round 8
// baseline (749.145 us; speedup 1.0000x reference)
//
#include <hip/hip_runtime.h>
#include <hip/hip_bf16.h>
#include <hip/hip_fp16.h>

#define SEQ 8192
#define DM  1024   // d_in == d_out == 1024

typedef __attribute__((ext_vector_type(8))) short    bf16x8;
typedef __attribute__((ext_vector_type(8))) _Float16 f16x8;
typedef __attribute__((ext_vector_type(4))) float    f32x4;

union H8 { _Float16 h[8]; int4 v; };

__device__ __forceinline__ unsigned short f2bf(float f) {
    union { float f; unsigned u; } x; x.f = f;
    unsigned r = x.u + 0x7fffu + ((x.u >> 16) & 1u);
    return (unsigned short)(r >> 16);
}
__device__ __forceinline__ float bf2f(unsigned short h) {
    union { unsigned u; float f; } x; x.u = ((unsigned)h) << 16;
    return x.f;
}

// async global->LDS, 16B per lane; lds dest wave-uniform base (HW adds lane*16)
__device__ __forceinline__ void gld16(const unsigned short* g, unsigned short* l) {
    __builtin_amdgcn_global_load_lds(
        (const __attribute__((address_space(1))) void*)g,
        (__attribute__((address_space(3))) void*)l, 16, 0, 0);
}

// ------- merged prep: blocks [0,8192) split x; blocks [8192,8960) transpose+split W -------
__global__ __launch_bounds__(256) void prep_kernel(const float* __restrict__ x,
    unsigned short* __restrict__ xhi, unsigned short* __restrict__ xlo,
    const float* W0, const float* W1, const float* W2,
    unsigned short* H0, unsigned short* L0,
    unsigned short* H1, unsigned short* L1,
    unsigned short* H2, unsigned short* L2)
{
    __shared__ float tile[64][65];
    int t = threadIdx.x;

    if (blockIdx.x < 8192) {
        // ---- split x (fp32 -> bf16 hi/lo), 1024 elems per block ----
        int base = (blockIdx.x * 256 + t) * 4;
        float4 v = *(const float4*)(x + base);
        float f[4] = {v.x, v.y, v.z, v.w};
        unsigned short h[4], l[4];
#pragma unroll
        for (int j = 0; j < 4; j++) { h[j] = f2bf(f[j]); l[j] = f2bf(f[j] - bf2f(h[j])); }
        ushort4 hv = {h[0], h[1], h[2], h[3]};
        ushort4 lv = {l[0], l[1], l[2], l[3]};
        *(ushort4*)(xhi + base) = hv;
        *(ushort4*)(xlo + base) = lv;
        return;
    }

    // ---- transpose + split W [1024k x 1024n] -> Wt hi/lo [n][k] ----
    int id = blockIdx.x - 8192;          // 0..767
    int z  = id >> 8;                    // which W
    int rem = id & 255;
    int bn = (rem & 15) * 64;
    int bk = (rem >> 4) * 64;
    const float* W = (z == 0) ? W0 : (z == 1) ? W1 : W2;
    unsigned short* Wthi = (z == 0) ? H0 : (z == 1) ? H1 : H2;
    unsigned short* Wtlo = (z == 0) ? L0 : (z == 1) ? L1 : L2;

#pragma unroll
    for (int p = 0; p < 4; p++) {
        int r = p * 16 + (t >> 4);
        int c = (t & 15) * 4;
        float4 v = *(const float4*)(W + (size_t)(bk + r) * DM + bn + c);
        tile[r][c] = v.x; tile[r][c+1] = v.y; tile[r][c+2] = v.z; tile[r][c+3] = v.w;
    }
    __syncthreads();
#pragma unroll
    for (int p = 0; p < 2; p++) {
        int task = p * 256 + t;
        int rn = task >> 3;
        int kc = (task & 7) * 8;
        union { unsigned short u[8]; int4 v; } hh, ll;
#pragma unroll
        for (int j = 0; j < 8; j++) {
            float f = tile[kc + j][rn];
            hh.u[j] = f2bf(f);
            ll.u[j] = f2bf(f - bf2f(hh.u[j]));
        }
        size_t o = (size_t)(bn + rn) * DM + bk + kc;
        *(int4*)(Wthi + o) = hh.v;
        *(int4*)(Wtlo + o) = ll.v;
    }
}

// ============ 128x128-tile GEMM, 256 thr (4 waves, 64x64 each), BK=32 ============
// R7 (verified): 1-barrier-per-K-tile schedule, 2 blocks/CU, both-sides LDS swizzle.
// R8: operand-ordered reads + row-pipelined MFMA. DS returns are IN-ORDER in the lgkm
// domain, so reading A before B made the first MFMA wait on ~all reads (full LDS|MFMA
// serialization, measured 54% MfmaUtil = serial-sum). New order: B fragments first,
// then per M-row {issue next row's A reads | this row's MFMAs} — each MFMA row waits
// only lgkmcnt(reads-in-flight-for-next-row). sched_group_barrier pins the interleave
// against the compiler's DS-clustering (counts match emitted instructions exactly).
// MODE 0: split bf16 -> split bf16 out (Q,K proj). MODE 1: bf16 -> f16 (V proj).
// MODE 3: PV with fused softmax scale from LDS-staged Sc (R6, verified numerics).
template<int MODE, int KD>
__global__ __launch_bounds__(256, 2) void gemm128(
    const unsigned short* A,   const unsigned short* Alo,
    const unsigned short* B_,  const unsigned short* Blo_,
    const unsigned short* B2,  const unsigned short* B2lo,
    unsigned short* Chi_, unsigned short* Clo_,
    unsigned short* Chi2, unsigned short* Clo2,
    _Float16* Cf16, float* Cf32, const float* __restrict__ Scp)
{
    constexpr bool SPLIT = (MODE == 0);
    constexpr int NT = KD / 32;
    __shared__ alignas(16) unsigned short sAhi[2][128 * 32];
    __shared__ alignas(16) unsigned short sBhi[2][128 * 32];
    __shared__ alignas(16) unsigned short sAlo[SPLIT ? 2 * 128 * 32 : 16];
    __shared__ alignas(16) unsigned short sBlo[SPLIT ? 2 * 128 * 32 : 16];
    __shared__ alignas(16) _Float16 sSc[(MODE == 3) ? 128 * 130 : 8];

    const unsigned short* B   = B_;
    const unsigned short* Blo = Blo_;
    unsigned short* Chi = Chi_;
    unsigned short* Clo = Clo_;
    if (MODE == 0 && blockIdx.z == 1) { B = B2; Blo = B2lo; Chi = Chi2; Clo = Clo2; }

    const int m0 = blockIdx.x * 128;
    const int n0 = blockIdx.y * 128;
    const int t = threadIdx.x;
    const int wave = t >> 6, lane = t & 63;
    const int wr = wave >> 1, wc = wave & 1;    // wave quadrant (64x64)
    const int i16 = lane & 15, quad = lane >> 4;

    // staging: wave stages rows wave*32 .. +31; source col pre-swizzled (rule 21)
    const int rs = wave * 32 + (lane >> 2);
    const int scol = ((lane & 3) ^ ((lane >> 3) & 3)) << 3;
    const size_t aoff = (size_t)(m0 + rs) * KD + scol;
    const size_t boff = (size_t)(n0 + rs) * KD + scol;
    const int ldsb = wave * 1024;   // element offset of this wave's staging region

    // read-side swizzled fragment offsets (loop-invariant)
    int offA[4], offB[4];
#pragma unroll
    for (int mt = 0; mt < 4; mt++) {
        int row = wr * 64 + mt * 16 + i16;
        offA[mt] = row * 32 + ((quad ^ ((row >> 1) & 3)) << 3);
    }
#pragma unroll
    for (int nt = 0; nt < 4; nt++) {
        int row = wc * 64 + nt * 16 + i16;
        offB[nt] = row * 32 + ((quad ^ ((row >> 1) & 3)) << 3);
    }

    // ---- MODE 3: one-time Sc slice -> LDS (f16), coalesced float4 reads ----
    if constexpr (MODE == 3) {
#pragma unroll
        for (int i = 0; i < 16; i++) {
            int idx = i * 1024 + t * 4;          // element index, multiple of 4
            int row = idx >> 7, col = idx & 127;
            float4 v = *(const float4*)(Scp + (size_t)(m0 + row) * 128 + col);
            _Float16* d = sSc + row * 130 + col;
            d[0] = (_Float16)v.x; d[1] = (_Float16)v.y;
            d[2] = (_Float16)v.z; d[3] = (_Float16)v.w;
        }
    }

    auto STAGE = [&](int buf, int k) {
        gld16(A + aoff + k,           sAhi[buf] + ldsb);
        gld16(A + aoff + 16 * KD + k, sAhi[buf] + ldsb + 512);
        gld16(B + boff + k,           sBhi[buf] + ldsb);
        gld16(B + boff + 16 * KD + k, sBhi[buf] + ldsb + 512);
        if constexpr (SPLIT) {
            gld16(Alo + aoff + k,           sAlo + buf * 4096 + ldsb);
            gld16(Alo + aoff + 16 * KD + k, sAlo + buf * 4096 + ldsb + 512);
            gld16(Blo + boff + k,           sBlo + buf * 4096 + ldsb);
            gld16(Blo + boff + 16 * KD + k, sBlo + buf * 4096 + ldsb + 512);
        }
    };

    f32x4 acc[4][4] = {};

    // prologue: stage tile 0; __syncthreads drains vmcnt (staging) AND lgkm (Sc writes)
    STAGE(0, 0);
    __syncthreads();

    for (int kt = 0; kt < NT; ++kt) {
        const int cur = kt & 1;
        const int k = kt * 32;

        // ---- B fragments + Sc + first A row (operand order: B before A!) ----
        bf16x8 bhi[4], blo[4];
#pragma unroll
        for (int nt = 0; nt < 4; nt++) {
            bhi[nt] = *(const bf16x8*)(sBhi[cur] + offB[nt]);
            if constexpr (SPLIT) blo[nt] = *(const bf16x8*)(sBlo + cur * 4096 + offB[nt]);
        }
        _Float16 scv[4];
        if constexpr (MODE == 3) {
#pragma unroll
            for (int mt = 0; mt < 4; mt++)
                scv[mt] = sSc[(wr * 64 + mt * 16 + i16) * 130 + (k >> 6)];
        }
        bf16x8 ahi, alo, ahin, aloin;
        ahi = *(const bf16x8*)(sAhi[cur] + offA[0]);
        if constexpr (SPLIT) alo = *(const bf16x8*)(sAlo + cur * 4096 + offA[0]);
        if constexpr (MODE == 3) {
            f16x8 av = __builtin_bit_cast(f16x8, ahi);
            av = av * scv[0];
            ahi = __builtin_bit_cast(bf16x8, av);
        }

        // ---- issue next tile's staging (drained at tile end) ----
        if (kt + 1 < NT) STAGE(cur ^ 1, k + 32);

        // ---- row-pipelined MFMA: read row mt+1 while computing row mt ----
        __builtin_amdgcn_s_setprio(1);
#pragma unroll
        for (int mt = 0; mt < 4; mt++) {
            if (mt < 3) {
                ahin = *(const bf16x8*)(sAhi[cur] + offA[mt + 1]);
                if constexpr (SPLIT) aloin = *(const bf16x8*)(sAlo + cur * 4096 + offA[mt + 1]);
            }
#pragma unroll
            for (int nt = 0; nt < 4; nt++) {
                if constexpr (MODE == 3) {
                    acc[mt][nt] = __builtin_amdgcn_mfma_f32_16x16x32_f16(
                        __builtin_bit_cast(f16x8, ahi), __builtin_bit_cast(f16x8, bhi[nt]),
                        acc[mt][nt], 0, 0, 0);
                } else {
                    acc[mt][nt] = __builtin_amdgcn_mfma_f32_16x16x32_bf16(ahi, bhi[nt], acc[mt][nt], 0, 0, 0);
                    if constexpr (SPLIT) {
                        acc[mt][nt] = __builtin_amdgcn_mfma_f32_16x16x32_bf16(ahi, blo[nt], acc[mt][nt], 0, 0, 0);
                        acc[mt][nt] = __builtin_amdgcn_mfma_f32_16x16x32_bf16(alo, bhi[nt], acc[mt][nt], 0, 0, 0);
                    }
                }
            }
            // pin interleave: this row's reads (for mt+1) then this row's MFMAs
            if (mt < 3) {
                __builtin_amdgcn_sched_group_barrier(0x100, SPLIT ? 2 : 1, 0); // DS_READ
                __builtin_amdgcn_sched_group_barrier(0x8, SPLIT ? 12 : 4, 0);  // MFMA
                ahi = ahin;
                if constexpr (SPLIT) alo = aloin;
                if constexpr (MODE == 3) {
                    f16x8 av = __builtin_bit_cast(f16x8, ahi);
                    av = av * scv[mt + 1];
                    ahi = __builtin_bit_cast(bf16x8, av);
                }
            } else {
                __builtin_amdgcn_sched_group_barrier(0x8, SPLIT ? 12 : 4, 0);  // MFMA
            }
        }
        __builtin_amdgcn_s_setprio(0);

        // ---- tile-end: drain next-tile staging, single barrier ----
        asm volatile("s_waitcnt vmcnt(0)" ::: "memory");
        __builtin_amdgcn_s_barrier();
        __builtin_amdgcn_sched_barrier(0);
    }

    // ---------------- epilogues ----------------
    if constexpr (MODE == 0) {
#pragma unroll
        for (int mt = 0; mt < 4; mt++)
#pragma unroll
            for (int nt = 0; nt < 4; nt++)
#pragma unroll
                for (int r = 0; r < 4; r++) {
                    int row = m0 + wr * 64 + mt * 16 + quad * 4 + r;
                    int col = n0 + wc * 64 + nt * 16 + i16;
                    float v = acc[mt][nt][r];
                    unsigned short h = f2bf(v);
                    Chi[(size_t)row * DM + col] = h;
                    Clo[(size_t)row * DM + col] = f2bf(v - bf2f(h));
                }
    } else if constexpr (MODE == 1) {
#pragma unroll
        for (int mt = 0; mt < 4; mt++)
#pragma unroll
            for (int nt = 0; nt < 4; nt++)
#pragma unroll
                for (int r = 0; r < 4; r++) {
                    int row = m0 + wr * 64 + mt * 16 + quad * 4 + r;
                    int col = n0 + wc * 64 + nt * 16 + i16;
                    Cf16[(size_t)row * DM + col] = (_Float16)acc[mt][nt][r];
                }
    } else {  // MODE 3: PV, f32 out
#pragma unroll
        for (int mt = 0; mt < 4; mt++)
#pragma unroll
            for (int nt = 0; nt < 4; nt++)
#pragma unroll
                for (int r = 0; r < 4; r++) {
                    int row = m0 + wr * 64 + mt * 16 + quad * 4 + r;
                    int col = n0 + wc * 64 + nt * 16 + i16;
                    Cf32[(size_t)row * DM + col] = acc[mt][nt][r];
                }
    }
}

// ============ scores: 256x256 tile, 512 thr (8 waves 2Mx4N), BK=32, split bf16 ============
// R3 schedule (1 barrier/K-tile) + R8 operand-ordered row-pipelined reads (see gemm128
// comment): B fragments first, then per M-row {next row's 2 A-reads | 12 MFMAs}, pinned
// with sched_group_barrier. LDS swizzle (R2, conflicts=0). XCD swizzle (R3).
__global__ __launch_bounds__(512, 2) void scores256(
    const unsigned short* __restrict__ Qh, const unsigned short* __restrict__ Ql,
    const unsigned short* __restrict__ Kh, const unsigned short* __restrict__ Kl,
    _Float16* __restrict__ Eo, float* __restrict__ Tt, float* __restrict__ Zt)
{
    constexpr int KD = 1024;
    constexpr int NT = KD / 32;                       // 32 K-tiles
    // layout: buf(0/1) x {Ahi,Alo,Bhi,Blo} x [256][32]  = 128 KiB
    __shared__ alignas(16) unsigned short lds[2 * 4 * 8192];

    // bijective XCD swizzle (nwg=1024 % 8 == 0); m-major within an XCD
    const int flat = blockIdx.y * gridDim.x + blockIdx.x;
    const int wg = (flat & 7) * 128 + (flat >> 3);
    const int m0 = (wg >> 5) << 8;
    const int n0 = (wg & 31) << 8;

    const int t = threadIdx.x;
    const int wave = t >> 6, lane = t & 63;
    const int wr = wave >> 2, wc = wave & 3;          // wave -> 128x64 output block
    const int i16 = lane & 15, quad = lane >> 4;

    const int srow = wave * 16 + (lane >> 2);
    const int scol = ((lane & 3) ^ ((lane >> 3) & 3)) << 3;
    const size_t ga = (size_t)(m0 + srow) * KD + scol;
    const size_t gb = (size_t)(n0 + srow) * KD + scol;
    const int ldw = wave * 512;                        // wave-uniform LDS el offset (round 0)

    // fragment LDS element offsets (loop-invariant, swizzled)
    int offA[8], offB[4];
#pragma unroll
    for (int mt = 0; mt < 8; mt++) {
        int row = wr * 128 + mt * 16 + i16;
        offA[mt] = row * 32 + ((quad ^ ((row >> 1) & 3)) << 3);
    }
#pragma unroll
    for (int nt = 0; nt < 4; nt++) {
        int row = wc * 64 + nt * 16 + i16;
        offB[nt] = row * 32 + ((quad ^ ((row >> 1) & 3)) << 3);
    }

    f32x4 acc[8][4] = {};

    auto STAGE = [&](int buf, int kt) {
        unsigned short* p = lds + buf * 32768;
        const int k = kt * 32;
#pragma unroll
        for (int i = 0; i < 2; i++) {
            const size_t gAo = ga + (size_t)(i * 128) * KD + k;
            const size_t gBo = gb + (size_t)(i * 128) * KD + k;
            const int lo = ldw + i * 4096;
            gld16(Qh + gAo, p + lo);
            gld16(Ql + gAo, p + 8192  + lo);
            gld16(Kh + gBo, p + 16384 + lo);
            gld16(Kl + gBo, p + 24576 + lo);
        }
    };

    // ---- prologue: stage tile 0 and DRAIN it (vmcnt, not lgkm!) before first reads ----
    STAGE(0, 0);
    asm volatile("s_waitcnt vmcnt(0)" ::: "memory");
    __builtin_amdgcn_s_barrier();
    __builtin_amdgcn_sched_barrier(0);

    for (int kt = 0; kt < NT; ++kt) {
        const int cur = kt & 1;
        const unsigned short* pAh = lds + cur * 32768;
        const unsigned short* pAl = pAh + 8192;
        const unsigned short* pBh = pAh + 16384;
        const unsigned short* pBl = pAh + 24576;

        // ---- B fragments first (8 reads), then A row 0 (2 reads) ----
        bf16x8 bh[4], bl[4];
#pragma unroll
        for (int ni = 0; ni < 4; ni++) {
            bh[ni] = *(const bf16x8*)(pBh + offB[ni]);
            bl[ni] = *(const bf16x8*)(pBl + offB[ni]);
        }
        bf16x8 ah, al, ahn, aln;
        ah = *(const bf16x8*)(pAh + offA[0]);
        al = *(const bf16x8*)(pAl + offA[0]);

        // ---- issue next tile's staging (drained at tile end, ~full tile of cover) ----
        if (kt + 1 < NT) STAGE(cur ^ 1, kt + 1);

        // ---- row-pipelined MFMA: read row mi+1 while computing row mi ----
        __builtin_amdgcn_s_setprio(1);
#pragma unroll
        for (int mi = 0; mi < 8; mi++) {
            if (mi < 7) {
                ahn = *(const bf16x8*)(pAh + offA[mi + 1]);
                aln = *(const bf16x8*)(pAl + offA[mi + 1]);
            }
#pragma unroll
            for (int ni = 0; ni < 4; ni++) {
                f32x4 c = acc[mi][ni];
                c = __builtin_amdgcn_mfma_f32_16x16x32_bf16(ah, bh[ni], c, 0, 0, 0);
                c = __builtin_amdgcn_mfma_f32_16x16x32_bf16(ah, bl[ni], c, 0, 0, 0);
                c = __builtin_amdgcn_mfma_f32_16x16x32_bf16(al, bh[ni], c, 0, 0, 0);
                acc[mi][ni] = c;
            }
            if (mi < 7) {
                __builtin_amdgcn_sched_group_barrier(0x100, 2, 0);  // 2 DS reads
                __builtin_amdgcn_sched_group_barrier(0x8, 12, 0);   // 12 MFMA
                ah = ahn; al = aln;
            } else {
                __builtin_amdgcn_sched_group_barrier(0x8, 12, 0);
            }
        }
        __builtin_amdgcn_s_setprio(0);

        // ---- tile-end: drain next-tile staging, single barrier ----
        asm volatile("s_waitcnt vmcnt(0)" ::: "memory");
        __builtin_amdgcn_s_barrier();
        __builtin_amdgcn_sched_barrier(0);
    }

    // ---- epilogue: E = exp(s - tile64max), Tt (max), Zt (sumexp) per 64-col tile ----
    const float scale = 0.03125f;  // 1/sqrt(1024)
    const int tix = (n0 + wc * 64) >> 6;
#pragma unroll
    for (int mt = 0; mt < 8; mt++)
#pragma unroll
        for (int r = 0; r < 4; r++) {
            float s0 = acc[mt][0][r] * scale, s1 = acc[mt][1][r] * scale;
            float s2 = acc[mt][2][r] * scale, s3 = acc[mt][3][r] * scale;
            float mx = fmaxf(fmaxf(s0, s1), fmaxf(s2, s3));
            mx = fmaxf(mx, __shfl_xor(mx, 1));
            mx = fmaxf(mx, __shfl_xor(mx, 2));
            mx = fmaxf(mx, __shfl_xor(mx, 4));
            mx = fmaxf(mx, __shfl_xor(mx, 8));
            float e0 = __expf(s0 - mx), e1 = __expf(s1 - mx);
            float e2 = __expf(s2 - mx), e3 = __expf(s3 - mx);
            float z = e0 + e1 + e2 + e3;
            z += __shfl_xor(z, 1);
            z += __shfl_xor(z, 2);
            z += __shfl_xor(z, 4);
            z += __shfl_xor(z, 8);
            int row = m0 + wr * 128 + mt * 16 + quad * 4 + r;
            if (i16 == 0) {
                Tt[(size_t)row * 128 + tix] = mx;
                Zt[(size_t)row * 128 + tix] = z;
            }
            size_t eb = (size_t)row * SEQ + n0 + wc * 64 + i16;
            Eo[eb +  0] = (_Float16)e0;
            Eo[eb + 16] = (_Float16)e1;
            Eo[eb + 32] = (_Float16)e2;
            Eo[eb + 48] = (_Float16)e3;
        }
}

// ---------------- transpose V [8192 x 1024] f16 -> Vt [1024 x 8192] ----------------
__global__ __launch_bounds__(256) void transpose_f16(const _Float16* __restrict__ in,
                                                     _Float16* __restrict__ out)
{
    __shared__ _Float16 tile[64][72];
    int bn = blockIdx.x * 64;
    int bm = blockIdx.y * 64;
    int t = threadIdx.x;
    int r = t >> 3, c = (t & 7) * 8;
#pragma unroll
    for (int p = 0; p < 2; p++) {
        int rr = p * 32 + r;
        H8 v; v.v = *(const int4*)(in + (size_t)(bm + rr) * DM + bn + c);
#pragma unroll
        for (int j = 0; j < 8; j++) tile[rr][c + j] = v.h[j];
    }
    __syncthreads();
#pragma unroll
    for (int p = 0; p < 2; p++) {
        int rr = p * 32 + r;
        H8 v;
#pragma unroll
        for (int j = 0; j < 8; j++) v.h[j] = tile[c + j][rr];
        *(int4*)(out + (size_t)(bn + rr) * SEQ + bm + c) = v.v;
    }
}

// ------- per-row softmax scale from per-tile stats: Sc[r][t] = e^{T-m}/l -------
__global__ __launch_bounds__(256) void sc_reduce(const float* __restrict__ Tt,
    const float* __restrict__ Zt, float* __restrict__ Sc)
{
    int row = blockIdx.x * 4 + (threadIdx.x >> 6);
    int lane = threadIdx.x & 63;
    size_t b = (size_t)row * 128 + lane;
    float t0 = Tt[b], t1 = Tt[b + 64];
    float z0 = Zt[b], z1 = Zt[b + 64];
    float m = fmaxf(t0, t1);
    for (int sh = 1; sh < 64; sh <<= 1) m = fmaxf(m, __shfl_xor(m, sh));
    float l = z0 * __expf(t0 - m) + z1 * __expf(t1 - m);
    for (int sh = 1; sh < 64; sh <<= 1) l += __shfl_xor(l, sh);
    float inv = 1.0f / l;
    Sc[b]      = __expf(t0 - m) * inv;
    Sc[b + 64] = __expf(t1 - m) * inv;
}

extern "C" void kernel_launch(void* const* d_in, const int* in_sizes, int n_in,
                              void* d_out, int out_size, void* d_ws, size_t ws_size,
                              hipStream_t stream)
{
    const float* x  = (const float*)d_in[0];
    const float* Wq = (const float*)d_in[1];
    const float* Wk = (const float*)d_in[2];
    const float* Wv = (const float*)d_in[3];
    float* Out = (float*)d_out;
    char* ws = (char*)d_ws;

    const size_t MB = 1024 * 1024;
    // Region [0, 128MB): first x-splits / W-splits / Vtmp, later E (after they are dead)
    unsigned short* xhi   = (unsigned short*)(ws + 0 * MB);
    unsigned short* xlo   = (unsigned short*)(ws + 16 * MB);
    unsigned short* Wqthi = (unsigned short*)(ws + 32 * MB);
    unsigned short* Wqtlo = (unsigned short*)(ws + 34 * MB);
    unsigned short* Wkthi = (unsigned short*)(ws + 36 * MB);
    unsigned short* Wktlo = (unsigned short*)(ws + 38 * MB);
    unsigned short* Wvthi = (unsigned short*)(ws + 40 * MB);
    unsigned short* Wvtlo = (unsigned short*)(ws + 42 * MB);
    _Float16*       Vtmp  = (_Float16*)     (ws + 44 * MB);   // dead after transpose
    _Float16*       E     = (_Float16*)     (ws + 0 * MB);    // 128 MB, written after splits dead

    size_t off = 128 * MB;
    unsigned short* Qhi = (unsigned short*)(ws + off); off += 16 * MB;
    unsigned short* Qlo = (unsigned short*)(ws + off); off += 16 * MB;
    unsigned short* Khi = (unsigned short*)(ws + off); off += 16 * MB;
    unsigned short* Klo = (unsigned short*)(ws + off); off += 16 * MB;
    _Float16*       Vt  = (_Float16*)      (ws + off); off += 16 * MB;
    float*          Tt  = (float*)         (ws + off); off += (size_t)SEQ * 128 * 4;
    float*          Zt  = (float*)         (ws + off); off += (size_t)SEQ * 128 * 4;
    float*          Sc  = (float*)         (ws + off); off += (size_t)SEQ * 128 * 4;

    // 1. split x + transpose/split all 3 weights, one launch
    prep_kernel<<<8192 + 768, 256, 0, stream>>>(x, xhi, xlo, Wq, Wk, Wv,
        Wqthi, Wqtlo, Wkthi, Wktlo, Wvthi, Wvtlo);
    // 2. Q and K projections (one launch)
    gemm128<0, DM><<<dim3(SEQ / 128, DM / 128, 2), 256, 0, stream>>>(
        xhi, xlo, Wqthi, Wqtlo, Wkthi, Wktlo,
        Qhi, Qlo, Khi, Klo, nullptr, nullptr, nullptr);
    // 3. V projection (row-major out)
    gemm128<1, DM><<<dim3(SEQ / 128, DM / 128), 256, 0, stream>>>(
        xhi, nullptr, Wvthi, nullptr, nullptr, nullptr,
        nullptr, nullptr, nullptr, nullptr, (_Float16*)Vtmp, nullptr, nullptr);
    // 4. transpose V
    transpose_f16<<<dim3(DM / 64, SEQ / 64), 256, 0, stream>>>(Vtmp, Vt);
    // 5. scores -> E (exp rel 64-col tile max), Tt, Zt   [256^2, row-pipelined]
    scores256<<<dim3(SEQ / 256, SEQ / 256), 512, 0, stream>>>(
        Qhi, Qlo, Khi, Klo, E, Tt, Zt);
    // 6. per-row/tile softmax scale (reads only 8 MB of stats)
    sc_reduce<<<SEQ / 4, 256, 0, stream>>>(Tt, Zt, Sc);
    // 7. O = P @ V with P = E*Sc fused via LDS-staged Sc (e_scale pass removed)
    gemm128<3, SEQ><<<dim3(SEQ / 128, DM / 128), 256, 0, stream>>>(
        (const unsigned short*)E, nullptr, (const unsigned short*)Vt, nullptr, nullptr, nullptr,
        nullptr, nullptr, nullptr, nullptr, nullptr, Out, Sc);
}

// Round 9
// 692.058 us; speedup vs baseline: 1.0825x; 1.0825x over previous
//
#include <hip/hip_runtime.h>
#include <hip/hip_bf16.h>
#include <hip/hip_fp16.h>

#define SEQ 8192
#define DM  1024   // d_in == d_out == 1024

typedef __attribute__((ext_vector_type(8))) short    bf16x8;
typedef __attribute__((ext_vector_type(8))) _Float16 f16x8;
typedef __attribute__((ext_vector_type(4))) float    f32x4;

union H8 { _Float16 h[8]; int4 v; };

__device__ __forceinline__ unsigned short f2bf(float f) {
    union { float f; unsigned u; } x; x.f = f;
    unsigned r = x.u + 0x7fffu + ((x.u >> 16) & 1u);
    return (unsigned short)(r >> 16);
}
__device__ __forceinline__ float bf2f(unsigned short h) {
    union { unsigned u; float f; } x; x.u = ((unsigned)h) << 16;
    return x.f;
}

// async global->LDS, 16B per lane; lds dest wave-uniform base (HW adds lane*16)
__device__ __forceinline__ void gld16(const unsigned short* g, unsigned short* l) {
    __builtin_amdgcn_global_load_lds(
        (const __attribute__((address_space(1))) void*)g,
        (__attribute__((address_space(3))) void*)l, 16, 0, 0);
}

// ------- merged prep: blocks [0,8192) split x; blocks [8192,8960) transpose+split W -------
__global__ __launch_bounds__(256) void prep_kernel(const float* __restrict__ x,
    unsigned short* __restrict__ xhi, unsigned short* __restrict__ xlo,
    const float* W0, const float* W1, const float* W2,
    unsigned short* H0, unsigned short* L0,
    unsigned short* H1, unsigned short* L1,
    unsigned short* H2, unsigned short* L2)
{
    __shared__ float tile[64][65];
    int t = threadIdx.x;

    if (blockIdx.x < 8192) {
        // ---- split x (fp32 -> bf16 hi/lo), 1024 elems per block ----
        int base = (blockIdx.x * 256 + t) * 4;
        float4 v = *(const float4*)(x + base);
        float f[4] = {v.x, v.y, v.z, v.w};
        unsigned short h[4], l[4];
#pragma unroll
        for (int j = 0; j < 4; j++) { h[j] = f2bf(f[j]); l[j] = f2bf(f[j] - bf2f(h[j])); }
        ushort4 hv = {h[0], h[1], h[2], h[3]};
        ushort4 lv = {l[0], l[1], l[2], l[3]};
        *(ushort4*)(xhi + base) = hv;
        *(ushort4*)(xlo + base) = lv;
        return;
    }

    // ---- transpose + split W [1024k x 1024n] -> Wt hi/lo [n][k] ----
    int id = blockIdx.x - 8192;          // 0..767
    int z  = id >> 8;                    // which W
    int rem = id & 255;
    int bn = (rem & 15) * 64;
    int bk = (rem >> 4) * 64;
    const float* W = (z == 0) ? W0 : (z == 1) ? W1 : W2;
    unsigned short* Wthi = (z == 0) ? H0 : (z == 1) ? H1 : H2;
    unsigned short* Wtlo = (z == 0) ? L0 : (z == 1) ? L1 : L2;

#pragma unroll
    for (int p = 0; p < 4; p++) {
        int r = p * 16 + (t >> 4);
        int c = (t & 15) * 4;
        float4 v = *(const float4*)(W + (size_t)(bk + r) * DM + bn + c);
        tile[r][c] = v.x; tile[r][c+1] = v.y; tile[r][c+2] = v.z; tile[r][c+3] = v.w;
    }
    __syncthreads();
#pragma unroll
    for (int p = 0; p < 2; p++) {
        int task = p * 256 + t;
        int rn = task >> 3;
        int kc = (task & 7) * 8;
        union { unsigned short u[8]; int4 v; } hh, ll;
#pragma unroll
        for (int j = 0; j < 8; j++) {
            float f = tile[kc + j][rn];
            hh.u[j] = f2bf(f);
            ll.u[j] = f2bf(f - bf2f(hh.u[j]));
        }
        size_t o = (size_t)(bn + rn) * DM + bk + kc;
        *(int4*)(Wthi + o) = hh.v;
        *(int4*)(Wtlo + o) = ll.v;
    }
}

// ============ 128x128-tile GEMM, 256 thr (4 waves, 64x64 each), BK=32 ============
// R7 (verified, 709.6us state): 1-barrier-per-K-tile schedule, 2 blocks/CU, both-sides
// LDS swizzle. R8's row-pipelined reads + sched_group_barrier REVERTED (regressed ~34us;
// T19 is null-as-graft, and intra-wave reorder can't desync the CU-global LDS FIFO).
// MODE 0: split bf16 -> split bf16 out (Q,K proj).
// MODE 1: bf16 -> f16 out written TRANSPOSED (R9): epilogue writes Vt[col][row] directly
//         (4 consecutive rows per lane = one 8B store) — replaces transpose_f16 + Vtmp.
// MODE 3: PV with fused softmax scale from LDS-staged Sc (R6, verified numerics).
template<int MODE, int KD>
__global__ __launch_bounds__(256, 2) void gemm128(
    const unsigned short* A,   const unsigned short* Alo,
    const unsigned short* B_,  const unsigned short* Blo_,
    const unsigned short* B2,  const unsigned short* B2lo,
    unsigned short* Chi_, unsigned short* Clo_,
    unsigned short* Chi2, unsigned short* Clo2,
    _Float16* Cf16, float* Cf32, const float* __restrict__ Scp)
{
    constexpr bool SPLIT = (MODE == 0);
    constexpr int NT = KD / 32;
    __shared__ alignas(16) unsigned short sAhi[2][128 * 32];
    __shared__ alignas(16) unsigned short sBhi[2][128 * 32];
    __shared__ alignas(16) unsigned short sAlo[SPLIT ? 2 * 128 * 32 : 16];
    __shared__ alignas(16) unsigned short sBlo[SPLIT ? 2 * 128 * 32 : 16];
    __shared__ alignas(16) _Float16 sSc[(MODE == 3) ? 128 * 130 : 8];

    const unsigned short* B   = B_;
    const unsigned short* Blo = Blo_;
    unsigned short* Chi = Chi_;
    unsigned short* Clo = Clo_;
    if (MODE == 0 && blockIdx.z == 1) { B = B2; Blo = B2lo; Chi = Chi2; Clo = Clo2; }

    const int m0 = blockIdx.x * 128;
    const int n0 = blockIdx.y * 128;
    const int t = threadIdx.x;
    const int wave = t >> 6, lane = t & 63;
    const int wr = wave >> 1, wc = wave & 1;    // wave quadrant (64x64)
    const int i16 = lane & 15, quad = lane >> 4;

    // staging: wave stages rows wave*32 .. +31; source col pre-swizzled (rule 21)
    const int rs = wave * 32 + (lane >> 2);
    const int scol = ((lane & 3) ^ ((lane >> 3) & 3)) << 3;
    const size_t aoff = (size_t)(m0 + rs) * KD + scol;
    const size_t boff = (size_t)(n0 + rs) * KD + scol;
    const int ldsb = wave * 1024;   // element offset of this wave's staging region

    // read-side swizzled fragment offsets (loop-invariant)
    int offA[4], offB[4];
#pragma unroll
    for (int mt = 0; mt < 4; mt++) {
        int row = wr * 64 + mt * 16 + i16;
        offA[mt] = row * 32 + ((quad ^ ((row >> 1) & 3)) << 3);
    }
#pragma unroll
    for (int nt = 0; nt < 4; nt++) {
        int row = wc * 64 + nt * 16 + i16;
        offB[nt] = row * 32 + ((quad ^ ((row >> 1) & 3)) << 3);
    }

    // ---- MODE 3: one-time Sc slice -> LDS (f16), coalesced float4 reads ----
    if constexpr (MODE == 3) {
#pragma unroll
        for (int i = 0; i < 16; i++) {
            int idx = i * 1024 + t * 4;          // element index, multiple of 4
            int row = idx >> 7, col = idx & 127;
            float4 v = *(const float4*)(Scp + (size_t)(m0 + row) * 128 + col);
            _Float16* d = sSc + row * 130 + col;
            d[0] = (_Float16)v.x; d[1] = (_Float16)v.y;
            d[2] = (_Float16)v.z; d[3] = (_Float16)v.w;
        }
    }

    auto STAGE = [&](int buf, int k) {
        gld16(A + aoff + k,           sAhi[buf] + ldsb);
        gld16(A + aoff + 16 * KD + k, sAhi[buf] + ldsb + 512);
        gld16(B + boff + k,           sBhi[buf] + ldsb);
        gld16(B + boff + 16 * KD + k, sBhi[buf] + ldsb + 512);
        if constexpr (SPLIT) {
            gld16(Alo + aoff + k,           sAlo + buf * 4096 + ldsb);
            gld16(Alo + aoff + 16 * KD + k, sAlo + buf * 4096 + ldsb + 512);
            gld16(Blo + boff + k,           sBlo + buf * 4096 + ldsb);
            gld16(Blo + boff + 16 * KD + k, sBlo + buf * 4096 + ldsb + 512);
        }
    };

    f32x4 acc[4][4] = {};

    // prologue: stage tile 0; __syncthreads drains vmcnt (staging) AND lgkm (Sc writes)
    STAGE(0, 0);
    __syncthreads();

    for (int kt = 0; kt < NT; ++kt) {
        const int cur = kt & 1;
        const int k = kt * 32;

        // ---- fragment reads from buf cur ----
        bf16x8 ahi[4], alo[4], bhi[4], blo[4];
#pragma unroll
        for (int mt = 0; mt < 4; mt++) {
            ahi[mt] = *(const bf16x8*)(sAhi[cur] + offA[mt]);
            if constexpr (SPLIT) alo[mt] = *(const bf16x8*)(sAlo + cur * 4096 + offA[mt]);
        }
#pragma unroll
        for (int nt = 0; nt < 4; nt++) {
            bhi[nt] = *(const bf16x8*)(sBhi[cur] + offB[nt]);
            if constexpr (SPLIT) blo[nt] = *(const bf16x8*)(sBlo + cur * 4096 + offB[nt]);
        }
        if constexpr (MODE == 3) {
#pragma unroll
            for (int mt = 0; mt < 4; mt++) {
                _Float16 sc = sSc[(wr * 64 + mt * 16 + i16) * 130 + (k >> 6)];
                f16x8 av = __builtin_bit_cast(f16x8, ahi[mt]);
                av = av * sc;
                ahi[mt] = __builtin_bit_cast(bf16x8, av);
            }
        }

        // ---- issue next tile's staging (drained at tile end) ----
        if (kt + 1 < NT) STAGE(cur ^ 1, k + 32);

        // ---- MFMA ----
        __builtin_amdgcn_s_setprio(1);
#pragma unroll
        for (int nt = 0; nt < 4; nt++)
#pragma unroll
            for (int mt = 0; mt < 4; mt++) {
                if constexpr (MODE == 3) {
                    acc[mt][nt] = __builtin_amdgcn_mfma_f32_16x16x32_f16(
                        __builtin_bit_cast(f16x8, ahi[mt]), __builtin_bit_cast(f16x8, bhi[nt]),
                        acc[mt][nt], 0, 0, 0);
                } else {
                    acc[mt][nt] = __builtin_amdgcn_mfma_f32_16x16x32_bf16(ahi[mt], bhi[nt], acc[mt][nt], 0, 0, 0);
                    if constexpr (SPLIT) {
                        acc[mt][nt] = __builtin_amdgcn_mfma_f32_16x16x32_bf16(ahi[mt], blo[nt], acc[mt][nt], 0, 0, 0);
                        acc[mt][nt] = __builtin_amdgcn_mfma_f32_16x16x32_bf16(alo[mt], bhi[nt], acc[mt][nt], 0, 0, 0);
                    }
                }
            }
        __builtin_amdgcn_s_setprio(0);

        // ---- tile-end: drain next-tile staging, single barrier ----
        asm volatile("s_waitcnt vmcnt(0)" ::: "memory");
        __builtin_amdgcn_s_barrier();
        __builtin_amdgcn_sched_barrier(0);
    }

    // ---------------- epilogues ----------------
    if constexpr (MODE == 0) {
#pragma unroll
        for (int mt = 0; mt < 4; mt++)
#pragma unroll
            for (int nt = 0; nt < 4; nt++)
#pragma unroll
                for (int r = 0; r < 4; r++) {
                    int row = m0 + wr * 64 + mt * 16 + quad * 4 + r;
                    int col = n0 + wc * 64 + nt * 16 + i16;
                    float v = acc[mt][nt][r];
                    unsigned short h = f2bf(v);
                    Chi[(size_t)row * DM + col] = h;
                    Clo[(size_t)row * DM + col] = f2bf(v - bf2f(h));
                }
    } else if constexpr (MODE == 1) {
        // transposed write: Vt[col][row], 4 consecutive rows per lane -> one 8B store
#pragma unroll
        for (int mt = 0; mt < 4; mt++)
#pragma unroll
            for (int nt = 0; nt < 4; nt++) {
                int row0 = m0 + wr * 64 + mt * 16 + quad * 4;
                int col  = n0 + wc * 64 + nt * 16 + i16;
                union { _Float16 h[4]; ushort2 u2[2]; unsigned long long q; } p;
#pragma unroll
                for (int r = 0; r < 4; r++) p.h[r] = (_Float16)acc[mt][nt][r];
                *(unsigned long long*)(Cf16 + (size_t)col * SEQ + row0) = p.q;
            }
    } else {  // MODE 3: PV, f32 out
#pragma unroll
        for (int mt = 0; mt < 4; mt++)
#pragma unroll
            for (int nt = 0; nt < 4; nt++)
#pragma unroll
                for (int r = 0; r < 4; r++) {
                    int row = m0 + wr * 64 + mt * 16 + quad * 4 + r;
                    int col = n0 + wc * 64 + nt * 16 + i16;
                    Cf32[(size_t)row * DM + col] = acc[mt][nt][r];
                }
    }
}

// ============ scores: 256x256 tile, 512 thr (8 waves 2Mx4N), BK=32, split bf16 ============
// R3 schedule (verified best for this kernel, 355us): ONE barrier per K-tile; staging for
// kt+1 issued at tile top, drained at tile end; LDS swizzle (R2, conflicts=0); XCD swizzle.
// R8's row-pipelining/SGB reverted (within noise to slightly negative).
__global__ __launch_bounds__(512, 2) void scores256(
    const unsigned short* __restrict__ Qh, const unsigned short* __restrict__ Ql,
    const unsigned short* __restrict__ Kh, const unsigned short* __restrict__ Kl,
    _Float16* __restrict__ Eo, float* __restrict__ Tt, float* __restrict__ Zt)
{
    constexpr int KD = 1024;
    constexpr int NT = KD / 32;                       // 32 K-tiles
    // layout: buf(0/1) x {Ahi,Alo,Bhi,Blo} x [256][32]  = 128 KiB
    __shared__ alignas(16) unsigned short lds[2 * 4 * 8192];

    // bijective XCD swizzle (nwg=1024 % 8 == 0); m-major within an XCD
    const int flat = blockIdx.y * gridDim.x + blockIdx.x;
    const int wg = (flat & 7) * 128 + (flat >> 3);
    const int m0 = (wg >> 5) << 8;
    const int n0 = (wg & 31) << 8;

    const int t = threadIdx.x;
    const int wave = t >> 6, lane = t & 63;
    const int wr = wave >> 2, wc = wave & 3;          // wave -> 128x64 output block
    const int i16 = lane & 15, quad = lane >> 4;

    const int srow = wave * 16 + (lane >> 2);
    const int scol = ((lane & 3) ^ ((lane >> 3) & 3)) << 3;
    const size_t ga = (size_t)(m0 + srow) * KD + scol;
    const size_t gb = (size_t)(n0 + srow) * KD + scol;
    const int ldw = wave * 512;                        // wave-uniform LDS el offset (round 0)

    // fragment LDS element offsets (loop-invariant, swizzled)
    int offA[8], offB[4];
#pragma unroll
    for (int mt = 0; mt < 8; mt++) {
        int row = wr * 128 + mt * 16 + i16;
        offA[mt] = row * 32 + ((quad ^ ((row >> 1) & 3)) << 3);
    }
#pragma unroll
    for (int nt = 0; nt < 4; nt++) {
        int row = wc * 64 + nt * 16 + i16;
        offB[nt] = row * 32 + ((quad ^ ((row >> 1) & 3)) << 3);
    }

    f32x4 acc[8][4] = {};

    auto STAGE = [&](int buf, int kt) {
        unsigned short* p = lds + buf * 32768;
        const int k = kt * 32;
#pragma unroll
        for (int i = 0; i < 2; i++) {
            const size_t gAo = ga + (size_t)(i * 128) * KD + k;
            const size_t gBo = gb + (size_t)(i * 128) * KD + k;
            const int lo = ldw + i * 4096;
            gld16(Qh + gAo, p + lo);
            gld16(Ql + gAo, p + 8192  + lo);
            gld16(Kh + gBo, p + 16384 + lo);
            gld16(Kl + gBo, p + 24576 + lo);
        }
    };

    // ---- prologue: stage tile 0 and DRAIN it (vmcnt, not lgkm!) before first reads ----
    STAGE(0, 0);
    asm volatile("s_waitcnt vmcnt(0)" ::: "memory");
    __builtin_amdgcn_s_barrier();
    __builtin_amdgcn_sched_barrier(0);

    for (int kt = 0; kt < NT; ++kt) {
        const int cur = kt & 1;
        const unsigned short* pAh = lds + cur * 32768;
        const unsigned short* pAl = pAh + 8192;
        const unsigned short* pBh = pAh + 16384;
        const unsigned short* pBl = pAh + 24576;

        bf16x8 ah[4], al[4], bh[4], bl[4];

        // ---- first A-half + all B fragments (16 ds_read_b128) ----
#pragma unroll
        for (int mi = 0; mi < 4; mi++) {
            ah[mi] = *(const bf16x8*)(pAh + offA[mi]);
            al[mi] = *(const bf16x8*)(pAl + offA[mi]);
        }
#pragma unroll
        for (int ni = 0; ni < 4; ni++) {
            bh[ni] = *(const bf16x8*)(pBh + offB[ni]);
            bl[ni] = *(const bf16x8*)(pBl + offB[ni]);
        }
        // ---- issue next tile's staging (drained at tile end, ~full tile of cover) ----
        if (kt + 1 < NT) STAGE(cur ^ 1, kt + 1);

        // ---- MFMA half 0 (rows 0..63 of wave tile), 48 MFMA ----
        __builtin_amdgcn_s_setprio(1);
#pragma unroll
        for (int mi = 0; mi < 4; mi++)
#pragma unroll
            for (int ni = 0; ni < 4; ni++) {
                f32x4 c = acc[mi][ni];
                c = __builtin_amdgcn_mfma_f32_16x16x32_bf16(ah[mi], bh[ni], c, 0, 0, 0);
                c = __builtin_amdgcn_mfma_f32_16x16x32_bf16(ah[mi], bl[ni], c, 0, 0, 0);
                c = __builtin_amdgcn_mfma_f32_16x16x32_bf16(al[mi], bh[ni], c, 0, 0, 0);
                acc[mi][ni] = c;
            }
        __builtin_amdgcn_s_setprio(0);

        // ---- second A-half (8 ds_read_b128) ----
#pragma unroll
        for (int mi = 0; mi < 4; mi++) {
            ah[mi] = *(const bf16x8*)(pAh + offA[4 + mi]);
            al[mi] = *(const bf16x8*)(pAl + offA[4 + mi]);
        }

        // ---- MFMA half 1 (rows 64..127), 48 MFMA ----
        __builtin_amdgcn_s_setprio(1);
#pragma unroll
        for (int mi = 0; mi < 4; mi++)
#pragma unroll
            for (int ni = 0; ni < 4; ni++) {
                f32x4 c = acc[4 + mi][ni];
                c = __builtin_amdgcn_mfma_f32_16x16x32_bf16(ah[mi], bh[ni], c, 0, 0, 0);
                c = __builtin_amdgcn_mfma_f32_16x16x32_bf16(ah[mi], bl[ni], c, 0, 0, 0);
                c = __builtin_amdgcn_mfma_f32_16x16x32_bf16(al[mi], bh[ni], c, 0, 0, 0);
                acc[4 + mi][ni] = c;
            }
        __builtin_amdgcn_s_setprio(0);

        // ---- tile-end: drain next-tile staging, single barrier ----
        asm volatile("s_waitcnt vmcnt(0)" ::: "memory");
        __builtin_amdgcn_s_barrier();
        __builtin_amdgcn_sched_barrier(0);
    }

    // ---- epilogue: E = exp(s - tile64max), Tt (max), Zt (sumexp) per 64-col tile ----
    const float scale = 0.03125f;  // 1/sqrt(1024)
    const int tix = (n0 + wc * 64) >> 6;
#pragma unroll
    for (int mt = 0; mt < 8; mt++)
#pragma unroll
        for (int r = 0; r < 4; r++) {
            float s0 = acc[mt][0][r] * scale, s1 = acc[mt][1][r] * scale;
            float s2 = acc[mt][2][r] * scale, s3 = acc[mt][3][r] * scale;
            float mx = fmaxf(fmaxf(s0, s1), fmaxf(s2, s3));
            mx = fmaxf(mx, __shfl_xor(mx, 1));
            mx = fmaxf(mx, __shfl_xor(mx, 2));
            mx = fmaxf(mx, __shfl_xor(mx, 4));
            mx = fmaxf(mx, __shfl_xor(mx, 8));
            float e0 = __expf(s0 - mx), e1 = __expf(s1 - mx);
            float e2 = __expf(s2 - mx), e3 = __expf(s3 - mx);
            float z = e0 + e1 + e2 + e3;
            z += __shfl_xor(z, 1);
            z += __shfl_xor(z, 2);
            z += __shfl_xor(z, 4);
            z += __shfl_xor(z, 8);
            int row = m0 + wr * 128 + mt * 16 + quad * 4 + r;
            if (i16 == 0) {
                Tt[(size_t)row * 128 + tix] = mx;
                Zt[(size_t)row * 128 + tix] = z;
            }
            size_t eb = (size_t)row * SEQ + n0 + wc * 64 + i16;
            Eo[eb +  0] = (_Float16)e0;
            Eo[eb + 16] = (_Float16)e1;
            Eo[eb + 32] = (_Float16)e2;
            Eo[eb + 48] = (_Float16)e3;
        }
}

// ------- per-row softmax scale from per-tile stats: Sc[r][t] = e^{T-m}/l -------
__global__ __launch_bounds__(256) void sc_reduce(const float* __restrict__ Tt,
    const float* __restrict__ Zt, float* __restrict__ Sc)
{
    int row = blockIdx.x * 4 + (threadIdx.x >> 6);
    int lane = threadIdx.x & 63;
    size_t b = (size_t)row * 128 + lane;
    float t0 = Tt[b], t1 = Tt[b + 64];
    float z0 = Zt[b], z1 = Zt[b + 64];
    float m = fmaxf(t0, t1);
    for (int sh = 1; sh < 64; sh <<= 1) m = fmaxf(m, __shfl_xor(m, sh));
    float l = z0 * __expf(t0 - m) + z1 * __expf(t1 - m);
    for (int sh = 1; sh < 64; sh <<= 1) l += __shfl_xor(l, sh);
    float inv = 1.0f / l;
    Sc[b]      = __expf(t0 - m) * inv;
    Sc[b + 64] = __expf(t1 - m) * inv;
}

extern "C" void kernel_launch(void* const* d_in, const int* in_sizes, int n_in,
                              void* d_out, int out_size, void* d_ws, size_t ws_size,
                              hipStream_t stream)
{
    const float* x  = (const float*)d_in[0];
    const float* Wq = (const float*)d_in[1];
    const float* Wk = (const float*)d_in[2];
    const float* Wv = (const float*)d_in[3];
    float* Out = (float*)d_out;
    char* ws = (char*)d_ws;

    const size_t MB = 1024 * 1024;
    // Region [0, 128MB): first x-splits / W-splits, later E (after they are dead)
    unsigned short* xhi   = (unsigned short*)(ws + 0 * MB);
    unsigned short* xlo   = (unsigned short*)(ws + 16 * MB);
    unsigned short* Wqthi = (unsigned short*)(ws + 32 * MB);
    unsigned short* Wqtlo = (unsigned short*)(ws + 34 * MB);
    unsigned short* Wkthi = (unsigned short*)(ws + 36 * MB);
    unsigned short* Wktlo = (unsigned short*)(ws + 38 * MB);
    unsigned short* Wvthi = (unsigned short*)(ws + 40 * MB);
    unsigned short* Wvtlo = (unsigned short*)(ws + 42 * MB);
    _Float16*       E     = (_Float16*)     (ws + 0 * MB);    // 128 MB, written after splits dead

    size_t off = 128 * MB;
    unsigned short* Qhi = (unsigned short*)(ws + off); off += 16 * MB;
    unsigned short* Qlo = (unsigned short*)(ws + off); off += 16 * MB;
    unsigned short* Khi = (unsigned short*)(ws + off); off += 16 * MB;
    unsigned short* Klo = (unsigned short*)(ws + off); off += 16 * MB;
    _Float16*       Vt  = (_Float16*)      (ws + off); off += 16 * MB;
    float*          Tt  = (float*)         (ws + off); off += (size_t)SEQ * 128 * 4;
    float*          Zt  = (float*)         (ws + off); off += (size_t)SEQ * 128 * 4;
    float*          Sc  = (float*)         (ws + off); off += (size_t)SEQ * 128 * 4;

    // 1. split x + transpose/split all 3 weights, one launch
    prep_kernel<<<8192 + 768, 256, 0, stream>>>(x, xhi, xlo, Wq, Wk, Wv,
        Wqthi, Wqtlo, Wkthi, Wktlo, Wvthi, Wvtlo);
    // 2. Q and K projections (one launch)
    gemm128<0, DM><<<dim3(SEQ / 128, DM / 128, 2), 256, 0, stream>>>(
        xhi, xlo, Wqthi, Wqtlo, Wkthi, Wktlo,
        Qhi, Qlo, Khi, Klo, nullptr, nullptr, nullptr);
    // 3. V projection, output written TRANSPOSED directly to Vt (transpose pass removed)
    gemm128<1, DM><<<dim3(SEQ / 128, DM / 128), 256, 0, stream>>>(
        xhi, nullptr, Wvthi, nullptr, nullptr, nullptr,
        nullptr, nullptr, nullptr, nullptr, (_Float16*)Vt, nullptr, nullptr);
    // 4. scores -> E (exp rel 64-col tile max), Tt, Zt   [256^2, 1-barrier/K-tile]
    scores256<<<dim3(SEQ / 256, SEQ / 256), 512, 0, stream>>>(
        Qhi, Qlo, Khi, Klo, E, Tt, Zt);
    // 5. per-row/tile softmax scale (reads only 8 MB of stats)
    sc_reduce<<<SEQ / 4, 256, 0, stream>>>(Tt, Zt, Sc);
    // 6. O = P @ V with P = E*Sc fused via LDS-staged Sc (e_scale pass removed)
    gemm128<3, SEQ><<<dim3(SEQ / 128, DM / 128), 256, 0, stream>>>(
        (const unsigned short*)E, nullptr, (const unsigned short*)Vt, nullptr, nullptr, nullptr,
        nullptr, nullptr, nullptr, nullptr, nullptr, Out, Sc);
}